// Round 3
// baseline (1317.922 us; speedup 1.0000x reference)
//
#include <hip/hip_runtime.h>

#define B 8
#define C 64
#define N 4096
#define O 64
#define KNN 20
#define PQ 4
#define SPLIT 8
#define TC 64
#define NTILE (N / SPLIT / TC)   /* 8 tiles per unit */
#define NUNIT (B * 16 * SPLIT)   /* 128 rowgroups x 8 splits = 1024 */
#define BN_EPS 1e-5f
#define NEG_SLOPE 0.2f

// insert (r,m) into ascending-sorted top-KNN list, dropping old min d[0].
// precondition: r > d[0]
__device__ __forceinline__ void sorted_insert(float (&d)[KNN], int (&id)[KNN],
                                              float r, int m) {
    bool cp = true;  // d[0] < r
    #pragma unroll
    for (int j = 0; j < KNN - 1; ++j) {
        bool c = d[j + 1] < r;
        float nv = c ? d[j + 1] : (cp ? r : d[j]);
        int   ni = c ? id[j + 1] : (cp ? m : id[j]);
        d[j] = nv; id[j] = ni;
        cp = c;
    }
    d[KNN - 1]  = cp ? r : d[KNN - 1];
    id[KNN - 1] = cp ? m : id[KNN - 1];
}

// -------- K0: transpose x (B,C,N) -> Xt (B,N,C), compute sq[b][n] = ||x_n||^2
__global__ __launch_bounds__(256) void k_transpose(const float* __restrict__ x,
                                                   float* __restrict__ Xt,
                                                   float* __restrict__ sq) {
    __shared__ float lds[C][65];
    int b    = blockIdx.x >> 6;
    int n0   = (blockIdx.x & 63) << 6;
    int lane = threadIdx.x & 63;
    int w    = threadIdx.x >> 6;
    #pragma unroll
    for (int i = 0; i < 16; ++i) {
        int c = w * 16 + i;
        lds[c][lane] = x[(size_t)b * C * N + (size_t)c * N + n0 + lane];
    }
    __syncthreads();
    #pragma unroll
    for (int i = 0; i < 16; ++i) {
        int nl = w * 16 + i;
        float v = lds[lane][nl];
        Xt[(size_t)b * N * C + (size_t)(n0 + nl) * C + lane] = v;
        float s = v * v;
        #pragma unroll
        for (int off = 32; off; off >>= 1) s += __shfl_xor(s, off, 64);
        if (lane == 0) sq[b * N + n0 + nl] = s;
    }
}

// -------- K1: a = X*(W1-W2)^T, bvec = X*W2^T
__global__ __launch_bounds__(256) void k_ab(const float* __restrict__ Xt,
                                            const float* __restrict__ W,
                                            float* __restrict__ av,
                                            float* __restrict__ bv) {
    int b  = blockIdx.x >> 5;
    int n0 = (blockIdx.x & 31) << 7;
    int o  = threadIdx.x & 63;
    int w  = __builtin_amdgcn_readfirstlane((int)(threadIdx.x >> 6));
    float wa[C], wb[C];
    #pragma unroll
    for (int c = 0; c < C; ++c) {
        float w1 = W[o * 2 * C + c];
        float w2 = W[o * 2 * C + C + c];
        wa[c] = w1 - w2;
        wb[c] = w2;
    }
    const float* xb = Xt + (size_t)b * N * C;
    for (int i = 0; i < 32; ++i) {
        int n = n0 + w * 32 + i;
        const float* xr = xb + (size_t)n * C;
        float aa = 0.f, bb = 0.f;
        #pragma unroll
        for (int c = 0; c < C; ++c) {
            float xc = xr[c];
            aa = fmaf(xc, wa[c], aa);
            bb = fmaf(xc, wb[c], bb);
        }
        size_t oidx = ((size_t)b * N + n) * O + o;
        av[oidx] = aa;
        bv[oidx] = bb;
    }
}

// -------- K2: LDS-tiled pairwise inner product + lazy-queue top-20, work-stealing
// unit u: rowgroup g = u>>3 (256 rows), split s = u&7 (512 candidates).
// 4 waves: wave w owns rows g*256 + w*64 + lane; all waves share LDS cand tiles.
__global__ void k_knn(const float* __restrict__ Xt,
                      const float* __restrict__ sq,
                      float* __restrict__ pdg,
                      int* __restrict__ pig,
                      int* __restrict__ ctr) {
    __shared__ float tile[2][TC * C];   // 2 x 16 KB
    __shared__ float tsq[2][TC];
    __shared__ int s_u;
    int tid  = threadIdx.x;
    int lane = tid & 63;
    int w    = __builtin_amdgcn_readfirstlane(tid >> 6);

    for (;;) {
        if (tid == 0) s_u = atomicAdd(ctr, 1);
        __syncthreads();
        int u = s_u;
        if (u >= NUNIT) break;
        int s   = u & (SPLIT - 1);
        int g   = u >> 3;
        int b   = g >> 4;
        int row = (g & 15) * 256 + w * 64 + lane;
        const float* xb  = Xt + (size_t)b * N * C;
        const float* sqb = sq + b * N;
        int m0 = s * (N / SPLIT);

        float q[C];
        #pragma unroll
        for (int c = 0; c < C; c += 4) {
            float4 v = *(const float4*)(xb + (size_t)row * C + c);
            q[c] = 2.f * v.x; q[c + 1] = 2.f * v.y;
            q[c + 2] = 2.f * v.z; q[c + 3] = 2.f * v.w;
        }
        float d[KNN]; int id[KNN];
        #pragma unroll
        for (int j = 0; j < KNN; ++j) { d[j] = -3.4e38f; id[j] = 0; }
        float pv[PQ]; int pi[PQ]; int pc = 0;
        #pragma unroll
        for (int j = 0; j < PQ; ++j) { pv[j] = 0.f; pi[j] = 0; }

        // stage tile 0 into buf 0
        {
            const float* src = xb + (size_t)m0 * C;
            #pragma unroll
            for (int j = 0; j < 4; ++j)
                *(float4*)&tile[0][j * 1024 + tid * 4] = *(const float4*)(src + j * 1024 + tid * 4);
            if (tid < TC) tsq[0][tid] = sqb[m0 + tid];
        }
        __syncthreads();

        auto proc = [&](int cur, int lo, int hi, int mbase) {
            for (int m = lo; m < hi; ++m) {
                const float* cp = &tile[cur][m * C];   // wave-uniform -> ds broadcast
                float a0 = 0.f, a1 = 0.f, a2 = 0.f, a3 = 0.f;
                #pragma unroll
                for (int cc = 0; cc < C / 4; ++cc) {
                    float4 v = *(const float4*)(cp + cc * 4);
                    a0 = fmaf(v.x, q[cc * 4 + 0], a0);
                    a1 = fmaf(v.y, q[cc * 4 + 1], a1);
                    a2 = fmaf(v.z, q[cc * 4 + 2], a2);
                    a3 = fmaf(v.w, q[cc * 4 + 3], a3);
                }
                float r = ((a0 + a1) + (a2 + a3)) - tsq[cur][m];
                if (r > d[0]) {
                    #pragma unroll
                    for (int j = 0; j < PQ; ++j) {
                        bool sel = (pc == j);
                        pv[j] = sel ? r : pv[j];
                        pi[j] = sel ? (mbase + m) : pi[j];
                    }
                    ++pc;
                }
                if (__any(pc == PQ)) {
                    #pragma unroll
                    for (int j = 0; j < PQ; ++j)
                        if (j < pc && pv[j] > d[0]) sorted_insert(d, id, pv[j], pi[j]);
                    pc = 0;
                }
            }
        };

        for (int t = 0; t < NTILE; ++t) {
            int cur = t & 1;
            int mbase = m0 + t * TC;
            float4 ld[4]; float lsq = 0.f;
            bool have = (t + 1 < NTILE);
            if (have) {            // issue next tile's loads (latency overlapped below)
                const float* src = xb + (size_t)(m0 + (t + 1) * TC) * C;
                #pragma unroll
                for (int j = 0; j < 4; ++j)
                    ld[j] = *(const float4*)(src + j * 1024 + tid * 4);
                if (tid < TC) lsq = sqb[m0 + (t + 1) * TC + tid];
            }
            proc(cur, 0, TC / 2, mbase);      // compute first half while loads fly
            if (have) {
                #pragma unroll
                for (int j = 0; j < 4; ++j)
                    *(float4*)&tile[cur ^ 1][j * 1024 + tid * 4] = ld[j];
                if (tid < TC) tsq[cur ^ 1][tid] = lsq;
            }
            proc(cur, TC / 2, TC, mbase);
            __syncthreads();
        }
        #pragma unroll
        for (int j = 0; j < PQ; ++j)          // final flush
            if (j < pc && pv[j] > d[0]) sorted_insert(d, id, pv[j], pi[j]);

        size_t rr = (size_t)b * N + row;
        float* po = pdg + (rr * SPLIT + s) * KNN;
        int*   qo = pig + (rr * SPLIT + s) * KNN;
        #pragma unroll
        for (int j = 0; j < KNN; ++j) { po[j] = d[j]; qo[j] = id[j]; }
    }
}

// -------- K2b: merge 8 sorted partial lists per row -> knn indices
__global__ __launch_bounds__(256) void k_merge(const float* __restrict__ pdg,
                                               const int* __restrict__ pig,
                                               int* __restrict__ knn) {
    int tid = threadIdx.x;
    size_t rr = (size_t)blockIdx.x * 256 + tid;
    const float* pr = pdg + rr * (SPLIT * KNN);
    const int*   qr = pig + rr * (SPLIT * KNN);
    float d[KNN]; int id[KNN];
    #pragma unroll
    for (int j = 0; j < KNN; ++j) { d[j] = pr[j]; id[j] = qr[j]; }
    for (int li = 1; li < SPLIT; ++li) {
        const float* lp = pr + li * KNN;
        const int*   lq = qr + li * KNN;
        for (int j = KNN - 1; j >= 0; --j) {   // descending; early-exit when dead
            float r = lp[j];
            if (!__any(r > d[0])) break;
            if (r > d[0]) sorted_insert(d, id, r, lq[j]);
        }
    }
    int* op = knn + rr * KNN;
    #pragma unroll
    for (int j = 0; j < KNN; ++j) op[j] = id[j];
}

// -------- K3: out[b][o][n] = leaky(scale*(a[n][o] + max_k bvec[idx_k][o]) + bias)
__global__ __launch_bounds__(256) void k_out(const float* __restrict__ av,
                                             const float* __restrict__ bv,
                                             const int* __restrict__ knn,
                                             const float* __restrict__ gamma,
                                             const float* __restrict__ beta,
                                             const float* __restrict__ rmean,
                                             const float* __restrict__ rvar,
                                             float* __restrict__ out) {
    __shared__ float lds[64][65];
    int b    = blockIdx.x >> 6;
    int n0   = (blockIdx.x & 63) << 6;
    int lane = threadIdx.x & 63;
    int w    = __builtin_amdgcn_readfirstlane((int)(threadIdx.x >> 6));
    int o    = lane;
    float scale = gamma[o] * rsqrtf(rvar[o] + BN_EPS);
    float bias  = fmaf(-rmean[o], scale, beta[o]);
    const float* bvb = bv + (size_t)b * N * O;
    for (int i = 0; i < 16; ++i) {
        int n = n0 + w * 16 + i;
        const int* kn = knn + ((size_t)b * N + n) * KNN;
        float mx = -3.4e38f, mn = 3.4e38f;
        #pragma unroll
        for (int j = 0; j < KNN; ++j) {
            float v = bvb[(size_t)kn[j] * O + o];
            mx = fmaxf(mx, v);
            mn = fminf(mn, v);
        }
        float a   = av[((size_t)b * N + n) * O + o];
        float sel = (scale >= 0.f) ? (a + mx) : (a + mn);
        float y   = fmaf(sel, scale, bias);
        y = fmaxf(y, NEG_SLOPE * y);
        lds[o][w * 16 + i] = y;
    }
    __syncthreads();
    int r  = threadIdx.x >> 2;
    int c0 = (threadIdx.x & 3) << 4;
    float* ob = out + (size_t)b * O * N + (size_t)r * N + n0;
    #pragma unroll
    for (int j = 0; j < 16; j += 4) {
        float4 v;
        v.x = lds[r][c0 + j + 0];
        v.y = lds[r][c0 + j + 1];
        v.z = lds[r][c0 + j + 2];
        v.w = lds[r][c0 + j + 3];
        *(float4*)(ob + c0 + j) = v;
    }
}

extern "C" void kernel_launch(void* const* d_in, const int* in_sizes, int n_in,
                              void* d_out, int out_size, void* d_ws, size_t ws_size,
                              hipStream_t stream) {
    const float* x     = (const float*)d_in[0];
    const float* W     = (const float*)d_in[1];
    const float* gamma = (const float*)d_in[2];
    const float* beta  = (const float*)d_in[3];
    const float* rmean = (const float*)d_in[4];
    const float* rvar  = (const float*)d_in[5];
    float* out = (float*)d_out;

    float* ws  = (float*)d_ws;
    float* Xt  = ws;                         //  2,097,152 f
    float* sqn = ws + 2097152;               //     32,768 f
    float* av  = ws + 2129920;               //  2,097,152 f
    float* bvv = ws + 4227072;               //  2,097,152 f
    float* pd  = ws + 6324224;               //  5,242,880 f
    int*   pid = (int*)(ws + 11567104);      //  5,242,880 i
    int*   knn = (int*)(ws + 16809984);      //    655,360 i
    int*   ctr = (int*)(ws + 17465344);      //  ~70 MB total

    hipMemsetAsync(ctr, 0, 4, stream);
    k_transpose<<<512, 256, 0, stream>>>(x, Xt, sqn);
    k_ab<<<256, 256, 0, stream>>>(Xt, W, av, bvv);
    k_knn<<<1024, 256, 0, stream>>>(Xt, sqn, pd, pid, ctr);
    k_merge<<<128, 256, 0, stream>>>(pd, pid, knn);
    k_out<<<512, 256, 0, stream>>>(av, bvv, knn, gamma, beta, rmean, rvar, out);
}

// Round 4
// 1142.504 us; speedup vs baseline: 1.1535x; 1.1535x over previous
//
#include <hip/hip_runtime.h>

#define B 8
#define C 64
#define N 4096
#define O 64
#define KNN 20
#define PQ 4
#define SPLIT 8
#define TC 64
#define NTILE (N / SPLIT / TC)   /* 8 tiles per unit */
#define NUNIT (B * 16 * SPLIT)   /* 128 rowgroups x 8 splits = 1024 */
#define BN_EPS 1e-5f
#define NEG_SLOPE 0.2f

// async global->LDS, no VGPR round-trip. LDS dest must be lane-contiguous.
__device__ __forceinline__ void gld16(const float* g, float* l) {
    __builtin_amdgcn_global_load_lds((const __attribute__((address_space(1))) void*)g,
                                     (__attribute__((address_space(3))) void*)l, 16, 0, 0);
}
__device__ __forceinline__ void gld4(const float* g, float* l) {
    __builtin_amdgcn_global_load_lds((const __attribute__((address_space(1))) void*)g,
                                     (__attribute__((address_space(3))) void*)l, 4, 0, 0);
}

// insert (r,m) into ascending-sorted top-KNN list, dropping old min d[0].
// precondition: r > d[0]
__device__ __forceinline__ void sorted_insert(float (&d)[KNN], int (&id)[KNN],
                                              float r, int m) {
    bool cp = true;  // d[0] < r
    #pragma unroll
    for (int j = 0; j < KNN - 1; ++j) {
        bool c = d[j + 1] < r;
        float nv = c ? d[j + 1] : (cp ? r : d[j]);
        int   ni = c ? id[j + 1] : (cp ? m : id[j]);
        d[j] = nv; id[j] = ni;
        cp = c;
    }
    d[KNN - 1]  = cp ? r : d[KNN - 1];
    id[KNN - 1] = cp ? m : id[KNN - 1];
}

// -------- K0: transpose x (B,C,N) -> Xt (B,N,C), compute sq[b][n] = ||x_n||^2
__global__ __launch_bounds__(256) void k_transpose(const float* __restrict__ x,
                                                   float* __restrict__ Xt,
                                                   float* __restrict__ sq) {
    __shared__ float lds[C][65];
    int b    = blockIdx.x >> 6;
    int n0   = (blockIdx.x & 63) << 6;
    int lane = threadIdx.x & 63;
    int w    = threadIdx.x >> 6;
    #pragma unroll
    for (int i = 0; i < 16; ++i) {
        int c = w * 16 + i;
        lds[c][lane] = x[(size_t)b * C * N + (size_t)c * N + n0 + lane];
    }
    __syncthreads();
    #pragma unroll
    for (int i = 0; i < 16; ++i) {
        int nl = w * 16 + i;
        float v = lds[lane][nl];
        Xt[(size_t)b * N * C + (size_t)(n0 + nl) * C + lane] = v;
        float s = v * v;
        #pragma unroll
        for (int off = 32; off; off >>= 1) s += __shfl_xor(s, off, 64);
        if (lane == 0) sq[b * N + n0 + nl] = s;
    }
}

// -------- K1: a = X*(W1-W2)^T, bvec = X*W2^T
__global__ __launch_bounds__(256, 3) void k_ab(const float* __restrict__ Xt,
                                               const float* __restrict__ W,
                                               float* __restrict__ av,
                                               float* __restrict__ bv) {
    int b  = blockIdx.x >> 5;
    int n0 = (blockIdx.x & 31) << 7;
    int o  = threadIdx.x & 63;
    int w  = __builtin_amdgcn_readfirstlane((int)(threadIdx.x >> 6));
    float wa[C], wb[C];
    #pragma unroll
    for (int c = 0; c < C; ++c) {
        float w1 = W[o * 2 * C + c];
        float w2 = W[o * 2 * C + C + c];
        wa[c] = w1 - w2;
        wb[c] = w2;
    }
    const float* xb = Xt + (size_t)b * N * C;
    for (int i = 0; i < 32; ++i) {
        int n = n0 + w * 32 + i;
        const float* xr = xb + (size_t)n * C;  // wave-uniform -> scalar loads
        float aa = 0.f, bb = 0.f;
        #pragma unroll
        for (int c = 0; c < C; ++c) {
            float xc = xr[c];
            aa = fmaf(xc, wa[c], aa);
            bb = fmaf(xc, wb[c], bb);
        }
        size_t oidx = ((size_t)b * N + n) * O + o;
        av[oidx] = aa;
        bv[oidx] = bb;
    }
}

// -------- K2: LDS-tiled pairwise inner product + lazy-queue top-20, work-stealing
// unit u: rowgroup g = u>>3 (256 rows), split s = u&7 (512 candidates).
// 4 waves: wave w owns rows g*256 + w*64 + lane; waves share async LDS cand tiles.
__global__ __launch_bounds__(256, 3) void k_knn(const float* __restrict__ Xt,
                                                const float* __restrict__ sq,
                                                float* __restrict__ pdg,
                                                int* __restrict__ pig,
                                                int* __restrict__ ctr) {
    __shared__ float tile[2][TC * C];   // 2 x 16 KB
    __shared__ float tsq[2][TC];
    __shared__ int s_u;
    int tid  = threadIdx.x;
    int lane = tid & 63;
    int w    = __builtin_amdgcn_readfirstlane(tid >> 6);

    for (;;) {
        if (tid == 0) s_u = atomicAdd(ctr, 1);
        __syncthreads();
        int u = s_u;
        if (u >= NUNIT) break;
        int s   = u & (SPLIT - 1);
        int g   = u >> 3;
        int b   = g >> 4;
        int row = (g & 15) * 256 + w * 64 + lane;
        const float* xb  = Xt + (size_t)b * N * C;
        const float* sqb = sq + b * N;
        int m0 = s * (N / SPLIT);

        // stage tile 0 (async, drained at the next barrier)
        {
            const float* src = xb + (size_t)m0 * C;
            #pragma unroll
            for (int j = 0; j < 4; ++j)
                gld16(src + j * 1024 + tid * 4, &tile[0][j * 1024 + tid * 4]);
            if (tid < TC) gld4(sqb + m0 + tid, &tsq[0][tid]);
        }

        float q[C];
        #pragma unroll
        for (int c = 0; c < C; c += 4) {
            float4 v = *(const float4*)(xb + (size_t)row * C + c);
            q[c] = 2.f * v.x; q[c + 1] = 2.f * v.y;
            q[c + 2] = 2.f * v.z; q[c + 3] = 2.f * v.w;
        }
        float d[KNN]; int id[KNN];
        #pragma unroll
        for (int j = 0; j < KNN; ++j) { d[j] = -3.4e38f; id[j] = 0; }
        float pv[PQ]; int pi[PQ]; int pc = 0;
        #pragma unroll
        for (int j = 0; j < PQ; ++j) { pv[j] = 0.f; pi[j] = 0; }

        __syncthreads();   // tile 0 + tsq 0 landed

        for (int t = 0; t < NTILE; ++t) {
            int cur = t & 1;
            if (t + 1 < NTILE) {   // async-stage next tile into other buffer
                const float* src = xb + (size_t)(m0 + (t + 1) * TC) * C;
                #pragma unroll
                for (int j = 0; j < 4; ++j)
                    gld16(src + j * 1024 + tid * 4, &tile[cur ^ 1][j * 1024 + tid * 4]);
                if (tid < TC) gld4(sqb + m0 + (t + 1) * TC + tid, &tsq[cur ^ 1][tid]);
            }
            int mbase = m0 + t * TC;
            for (int m = 0; m < TC; ++m) {
                const float* cp = &tile[cur][m * C];   // wave-uniform -> broadcast
                float a0 = 0.f, a1 = 0.f, a2 = 0.f, a3 = 0.f;
                #pragma unroll
                for (int cc = 0; cc < C / 4; ++cc) {
                    float4 v = *(const float4*)(cp + cc * 4);
                    a0 = fmaf(v.x, q[cc * 4 + 0], a0);
                    a1 = fmaf(v.y, q[cc * 4 + 1], a1);
                    a2 = fmaf(v.z, q[cc * 4 + 2], a2);
                    a3 = fmaf(v.w, q[cc * 4 + 3], a3);
                }
                float r = ((a0 + a1) + (a2 + a3)) - tsq[cur][m];
                if (r > d[0]) {                 // cheap append to pending queue
                    #pragma unroll
                    for (int j = 0; j < PQ; ++j) {
                        bool sel = (pc == j);
                        pv[j] = sel ? r : pv[j];
                        pi[j] = sel ? (mbase + m) : pi[j];
                    }
                    ++pc;
                }
                if (__any(pc == PQ)) {          // drain all lanes in parallel
                    #pragma unroll
                    for (int j = 0; j < PQ; ++j)
                        if (j < pc && pv[j] > d[0]) sorted_insert(d, id, pv[j], pi[j]);
                    pc = 0;
                }
            }
            __syncthreads();   // drains next tile's async loads + protects reuse
        }
        #pragma unroll
        for (int j = 0; j < PQ; ++j)            // final flush
            if (j < pc && pv[j] > d[0]) sorted_insert(d, id, pv[j], pi[j]);

        size_t rr = (size_t)b * N + row;
        float* po = pdg + (rr * SPLIT + s) * KNN;
        int*   qo = pig + (rr * SPLIT + s) * KNN;
        #pragma unroll
        for (int j = 0; j < KNN; ++j) { po[j] = d[j]; qo[j] = id[j]; }
    }
}

// -------- K2b: merge 8 sorted partial lists per row -> knn indices
__global__ __launch_bounds__(256) void k_merge(const float* __restrict__ pdg,
                                               const int* __restrict__ pig,
                                               int* __restrict__ knn) {
    int tid = threadIdx.x;
    size_t rr = (size_t)blockIdx.x * 256 + tid;
    const float* pr = pdg + rr * (SPLIT * KNN);
    const int*   qr = pig + rr * (SPLIT * KNN);
    float d[KNN]; int id[KNN];
    #pragma unroll
    for (int j = 0; j < KNN; ++j) { d[j] = pr[j]; id[j] = qr[j]; }
    for (int li = 1; li < SPLIT; ++li) {
        const float* lp = pr + li * KNN;
        const int*   lq = qr + li * KNN;
        for (int j = KNN - 1; j >= 0; --j) {   // descending; early-exit when dead
            float r = lp[j];
            if (!__any(r > d[0])) break;
            if (r > d[0]) sorted_insert(d, id, r, lq[j]);
        }
    }
    int* op = knn + rr * KNN;
    #pragma unroll
    for (int j = 0; j < KNN; ++j) op[j] = id[j];
}

// -------- K3: out[b][o][n] = leaky(scale*(a[n][o] + max_k bvec[idx_k][o]) + bias)
__global__ __launch_bounds__(256) void k_out(const float* __restrict__ av,
                                             const float* __restrict__ bv,
                                             const int* __restrict__ knn,
                                             const float* __restrict__ gamma,
                                             const float* __restrict__ beta,
                                             const float* __restrict__ rmean,
                                             const float* __restrict__ rvar,
                                             float* __restrict__ out) {
    __shared__ float lds[64][65];
    int b    = blockIdx.x >> 6;
    int n0   = (blockIdx.x & 63) << 6;
    int lane = threadIdx.x & 63;
    int w    = __builtin_amdgcn_readfirstlane((int)(threadIdx.x >> 6));
    int o    = lane;
    float scale = gamma[o] * rsqrtf(rvar[o] + BN_EPS);
    float bias  = fmaf(-rmean[o], scale, beta[o]);
    const float* bvb = bv + (size_t)b * N * O;
    for (int i = 0; i < 16; ++i) {
        int n = n0 + w * 16 + i;
        const int* kn = knn + ((size_t)b * N + n) * KNN;
        float mx = -3.4e38f, mn = 3.4e38f;
        #pragma unroll
        for (int j = 0; j < KNN; ++j) {
            float v = bvb[(size_t)kn[j] * O + o];
            mx = fmaxf(mx, v);
            mn = fminf(mn, v);
        }
        float a   = av[((size_t)b * N + n) * O + o];
        float sel = (scale >= 0.f) ? (a + mx) : (a + mn);
        float y   = fmaf(sel, scale, bias);
        y = fmaxf(y, NEG_SLOPE * y);
        lds[o][w * 16 + i] = y;
    }
    __syncthreads();
    int r  = threadIdx.x >> 2;
    int c0 = (threadIdx.x & 3) << 4;
    float* ob = out + (size_t)b * O * N + (size_t)r * N + n0;
    #pragma unroll
    for (int j = 0; j < 16; j += 4) {
        float4 v;
        v.x = lds[r][c0 + j + 0];
        v.y = lds[r][c0 + j + 1];
        v.z = lds[r][c0 + j + 2];
        v.w = lds[r][c0 + j + 3];
        *(float4*)(ob + c0 + j) = v;
    }
}

extern "C" void kernel_launch(void* const* d_in, const int* in_sizes, int n_in,
                              void* d_out, int out_size, void* d_ws, size_t ws_size,
                              hipStream_t stream) {
    const float* x     = (const float*)d_in[0];
    const float* W     = (const float*)d_in[1];
    const float* gamma = (const float*)d_in[2];
    const float* beta  = (const float*)d_in[3];
    const float* rmean = (const float*)d_in[4];
    const float* rvar  = (const float*)d_in[5];
    float* out = (float*)d_out;

    float* ws  = (float*)d_ws;
    float* Xt  = ws;                         //  2,097,152 f
    float* sqn = ws + 2097152;               //     32,768 f
    float* av  = ws + 2129920;               //  2,097,152 f
    float* bvv = ws + 4227072;               //  2,097,152 f
    float* pd  = ws + 6324224;               //  5,242,880 f
    int*   pid = (int*)(ws + 11567104);      //  5,242,880 i
    int*   knn = (int*)(ws + 16809984);      //    655,360 i
    int*   ctr = (int*)(ws + 17465344);      //  ~70 MB total

    hipMemsetAsync(ctr, 0, 4, stream);
    k_transpose<<<512, 256, 0, stream>>>(x, Xt, sqn);
    k_ab<<<256, 256, 0, stream>>>(Xt, W, av, bvv);
    k_knn<<<1024, 256, 0, stream>>>(Xt, sqn, pd, pid, ctr);
    k_merge<<<128, 256, 0, stream>>>(pd, pid, knn);
    k_out<<<512, 256, 0, stream>>>(av, bvv, knn, gamma, beta, rmean, rvar, out);
}

// Round 5
// 686.416 us; speedup vs baseline: 1.9200x; 1.6644x over previous
//
#include <hip/hip_runtime.h>

#define B 8
#define C 64
#define N 4096
#define O 64
#define KNN 20
#define PQ 4
#define SSTR 68          /* score-row stride in floats: 68%32=4 -> 2-way, free */
#define BN_EPS 1e-5f
#define NEG_SLOPE 0.2f

typedef _Float16 f16x8 __attribute__((ext_vector_type(8)));
typedef float    f32x4 __attribute__((ext_vector_type(4)));
#define MFMA16(a, b, c) __builtin_amdgcn_mfma_f32_16x16x32_f16(a, b, c, 0, 0, 0)

__device__ __forceinline__ void gld16(const float* g, float* l) {
    __builtin_amdgcn_global_load_lds((const __attribute__((address_space(1))) void*)g,
                                     (__attribute__((address_space(3))) void*)l, 16, 0, 0);
}
__device__ __forceinline__ void gld4(const float* g, float* l) {
    __builtin_amdgcn_global_load_lds((const __attribute__((address_space(1))) void*)g,
                                     (__attribute__((address_space(3))) void*)l, 4, 0, 0);
}

// insert (r,m) into ascending-sorted top-KNN list, dropping old min d[0].
__device__ __forceinline__ void sorted_insert(float (&d)[KNN], int (&id)[KNN],
                                              float r, int m) {
    bool cp = true;
    #pragma unroll
    for (int j = 0; j < KNN - 1; ++j) {
        bool c = d[j + 1] < r;
        float nv = c ? d[j + 1] : (cp ? r : d[j]);
        int   ni = c ? id[j + 1] : (cp ? m : id[j]);
        d[j] = nv; id[j] = ni;
        cp = c;
    }
    d[KNN - 1]  = cp ? r : d[KNN - 1];
    id[KNN - 1] = cp ? m : id[KNN - 1];
}

// -------- K0: x (B,C,N) -> Xt (B,N,C) fp32, sq = ||x_n||^2, and AHL: f16 hi/lo
// frag-major: per 16-row group (4096 B): [term][khalf][quad][slot16][8 f16]
// so an MFMA A/B fragment read is exactly base + lane*16 (lane-linear).
__global__ __launch_bounds__(256) void k_transpose(const float* __restrict__ x,
                                                   float* __restrict__ Xt,
                                                   float* __restrict__ sq,
                                                   char* __restrict__ AHL) {
    __shared__ float lds[C][65];
    int b    = blockIdx.x >> 6;
    int n0   = (blockIdx.x & 63) << 6;
    int lane = threadIdx.x & 63;
    int w    = threadIdx.x >> 6;
    #pragma unroll
    for (int i = 0; i < 16; ++i) {
        int c = w * 16 + i;
        lds[c][lane] = x[(size_t)b * C * N + (size_t)c * N + n0 + lane];
    }
    __syncthreads();
    #pragma unroll
    for (int i = 0; i < 16; ++i) {
        int nl = w * 16 + i;
        float v = lds[lane][nl];
        Xt[(size_t)b * N * C + (size_t)(n0 + nl) * C + lane] = v;
        float s = v * v;
        #pragma unroll
        for (int off = 32; off; off >>= 1) s += __shfl_xor(s, off, 64);
        if (lane == 0) sq[b * N + n0 + nl] = s;
    }
    // frag-major hi/lo emit: thread -> (slot s2, quad qd, khalf hh, term tt)
    int s2  = threadIdx.x & 15;
    int rem = threadIdx.x >> 4;
    int qd  = rem & 3;
    int hh  = (rem >> 2) & 1;
    int tt  = rem >> 3;
    int kb  = hh * 32 + qd * 8;
    for (int i = 0; i < 4; ++i) {          // 4 row-groups of 16 in this tile
        int rowl = i * 16 + s2;
        f16x8 pk;
        #pragma unroll
        for (int ii = 0; ii < 8; ++ii) {
            float v = lds[kb + ii][rowl];
            _Float16 hv = (_Float16)v;
            if (tt) hv = (_Float16)(v - (float)hv);
            pk[ii] = hv;
        }
        char* dst = AHL + ((size_t)b << 20) + (size_t)((n0 >> 4) + i) * 4096
                  + tt * 2048 + hh * 1024 + qd * 256 + s2 * 16;
        *(f16x8*)dst = pk;
    }
}

// -------- K1: a = X*(W1-W2)^T, bvec = X*W2^T
__global__ __launch_bounds__(256, 2) void k_ab(const float* __restrict__ Xt,
                                               const float* __restrict__ W,
                                               float* __restrict__ av,
                                               float* __restrict__ bv) {
    int b  = blockIdx.x >> 5;
    int n0 = (blockIdx.x & 31) << 7;
    int o  = threadIdx.x & 63;
    int w  = __builtin_amdgcn_readfirstlane((int)(threadIdx.x >> 6));
    float wa[C], wb[C];
    #pragma unroll
    for (int c = 0; c < C; ++c) {
        float w1 = W[o * 2 * C + c];
        float w2 = W[o * 2 * C + C + c];
        wa[c] = w1 - w2;
        wb[c] = w2;
    }
    const float* xb = Xt + (size_t)b * N * C;
    for (int i = 0; i < 32; ++i) {
        int n = n0 + w * 32 + i;
        const float* xr = xb + (size_t)n * C;
        float aa = 0.f, bb = 0.f;
        #pragma unroll
        for (int c = 0; c < C; ++c) {
            float xc = xr[c];
            aa = fmaf(xc, wa[c], aa);
            bb = fmaf(xc, wb[c], bb);
        }
        size_t oidx = ((size_t)b * N + n) * O + o;
        av[oidx] = aa;
        bv[oidx] = bb;
    }
}

// -------- K2: MFMA distance tiles (f16 hi/lo x3 split) + per-wave top-20 scan
// block: 64 query rows (rb), all 4096 candidates in 64-cand tiles.
// wave w: computes S[all 64 cands][rows w*16..+16); scans cands w*16..+16.
__global__ __launch_bounds__(256, 3) void k_knn(const char* __restrict__ AHL,
                                                const float* __restrict__ sq,
                                                int* __restrict__ knn) {
    __shared__ __align__(16) char smem[50688];
    char*  cb0 = smem;                         // 16 KB cand tile buf 0
    char*  cb1 = smem + 16384;                 // 16 KB cand tile buf 1
    float* S   = (float*)(smem + 32768);       // 64 x 68 floats = 17 KB
    float* tsq = (float*)(smem + 50176);       // 2 x 64 floats

    int b    = blockIdx.x >> 6;
    int rb   = blockIdx.x & 63;
    int n0   = rb << 6;
    int tid  = threadIdx.x;
    int lane = tid & 63;
    int w    = __builtin_amdgcn_readfirstlane(tid >> 6);
    const char*  AHLb = AHL + ((size_t)b << 20);
    const float* sqb  = sq + b * N;

    // B-frags: this wave's 16 query rows (group rb*4 + w), hi/lo x khalf
    const char* qb = AHLb + (size_t)(rb * 4 + w) * 4096;
    f16x8 bh0 = *(const f16x8*)(qb +    0 + lane * 16);
    f16x8 bh1 = *(const f16x8*)(qb + 1024 + lane * 16);
    f16x8 bl0 = *(const f16x8*)(qb + 2048 + lane * 16);
    f16x8 bl1 = *(const f16x8*)(qb + 3072 + lane * 16);

    float d[KNN]; int id[KNN];
    #pragma unroll
    for (int j = 0; j < KNN; ++j) { d[j] = -3.4e38f; id[j] = 0; }
    float pv[PQ]; int pi[PQ]; int pc = 0;
    #pragma unroll
    for (int j = 0; j < PQ; ++j) { pv[j] = 0.f; pi[j] = 0; }

    // stage tile 0
    {
        const char* src = AHLb;
        #pragma unroll
        for (int j = 0; j < 4; ++j) {
            int ch = (w * 4 + j) * 1024;
            gld16((const float*)(src + ch + lane * 16), (float*)(cb0 + ch + lane * 16));
        }
        if (tid < 64) gld4(sqb + tid, tsq + tid);
    }
    __syncthreads();

    for (int t = 0; t < 64; ++t) {
        char*  cur  = (t & 1) ? cb1 : cb0;
        char*  nxt  = (t & 1) ? cb0 : cb1;
        float* tsqc = tsq + (t & 1) * 64;
        if (t + 1 < 64) {   // async-stage next 64-cand tile
            const char* src = AHLb + (size_t)(t + 1) * 16384;
            #pragma unroll
            for (int j = 0; j < 4; ++j) {
                int ch = (w * 4 + j) * 1024;
                gld16((const float*)(src + ch + lane * 16), (float*)(nxt + ch + lane * 16));
            }
            if (tid < 64) gld4(sqb + (t + 1) * 64 + tid, tsq + ((t + 1) & 1) * 64 + tid);
        }
        // MFMA: 4 cand-groups x (hh + hl + lh), K=64 as 2x K32
        int colr = w * 16 + (lane & 15);
        #pragma unroll
        for (int cg = 0; cg < 4; ++cg) {
            const char* ct = cur + cg * 4096;
            f16x8 ah0 = *(const f16x8*)(ct +    0 + lane * 16);
            f16x8 ah1 = *(const f16x8*)(ct + 1024 + lane * 16);
            f16x8 al0 = *(const f16x8*)(ct + 2048 + lane * 16);
            f16x8 al1 = *(const f16x8*)(ct + 3072 + lane * 16);
            f32x4 acc = {0.f, 0.f, 0.f, 0.f};
            acc = MFMA16(ah0, bh0, acc);
            acc = MFMA16(ah1, bh1, acc);
            acc = MFMA16(ah0, bl0, acc);
            acc = MFMA16(ah1, bl1, acc);
            acc = MFMA16(al0, bh0, acc);
            acc = MFMA16(al1, bh1, acc);
            int cbase = cg * 16 + (lane >> 4) * 4;
            #pragma unroll
            for (int r = 0; r < 4; ++r)
                S[(cbase + r) * SSTR + colr] = acc[r];
        }
        __syncthreads();   // S complete (all waves' stripes)
        // scan: wave w handles cands [w*16, w*16+16), lane = query row
        #pragma unroll
        for (int jj = 0; jj < 16; ++jj) {
            int ml = w * 16 + jj;
            float sv = S[ml * SSTR + lane];
            float r  = fmaf(2.f, sv, -tsqc[ml]);
            int cand = t * 64 + ml;
            if (r > d[0]) {
                #pragma unroll
                for (int j = 0; j < PQ; ++j) {
                    bool sel = (pc == j);
                    pv[j] = sel ? r : pv[j];
                    pi[j] = sel ? cand : pi[j];
                }
                ++pc;
            }
            if (__any(pc == PQ)) {
                #pragma unroll
                for (int j = 0; j < PQ; ++j)
                    if (j < pc && pv[j] > d[0]) sorted_insert(d, id, pv[j], pi[j]);
                pc = 0;
            }
        }
        __syncthreads();   // scan done before next tile's MFMA overwrites S
    }
    #pragma unroll
    for (int j = 0; j < PQ; ++j)
        if (j < pc && pv[j] > d[0]) sorted_insert(d, id, pv[j], pi[j]);

    // in-block merge of the 4 waves' partial lists (overlay on dead LDS)
    float* md = (float*)smem;                   // [4][64][20] floats, 20 KB
    int*   mi = (int*)(smem + 20480);           // [4][64][20] ints,  20 KB
    __syncthreads();
    #pragma unroll
    for (int j = 0; j < KNN; ++j) {
        md[(w * 64 + lane) * KNN + j] = d[j];
        mi[(w * 64 + lane) * KNN + j] = id[j];
    }
    __syncthreads();
    if (w == 0) {
        #pragma unroll
        for (int ww = 1; ww < 4; ++ww) {
            const float* lp = md + (ww * 64 + lane) * KNN;
            const int*   lq = mi + (ww * 64 + lane) * KNN;
            for (int j = KNN - 1; j >= 0; --j) {
                float r = lp[j];
                if (!__any(r > d[0])) break;
                if (r > d[0]) sorted_insert(d, id, r, lq[j]);
            }
        }
        int* op = knn + ((size_t)b * N + n0 + lane) * KNN;
        #pragma unroll
        for (int j = 0; j < KNN; ++j) op[j] = id[j];
    }
}

// -------- K3: out[b][o][n] = leaky(scale*(a[n][o] + max_k bvec[idx_k][o]) + bias)
__global__ __launch_bounds__(256) void k_out(const float* __restrict__ av,
                                             const float* __restrict__ bv,
                                             const int* __restrict__ knn,
                                             const float* __restrict__ gamma,
                                             const float* __restrict__ beta,
                                             const float* __restrict__ rmean,
                                             const float* __restrict__ rvar,
                                             float* __restrict__ out) {
    __shared__ float lds[64][65];
    int b    = blockIdx.x >> 6;
    int n0   = (blockIdx.x & 63) << 6;
    int lane = threadIdx.x & 63;
    int w    = __builtin_amdgcn_readfirstlane((int)(threadIdx.x >> 6));
    int o    = lane;
    float scale = gamma[o] * rsqrtf(rvar[o] + BN_EPS);
    float bias  = fmaf(-rmean[o], scale, beta[o]);
    const float* bvb = bv + (size_t)b * N * O;
    for (int i = 0; i < 16; ++i) {
        int n = n0 + w * 16 + i;
        const int* kn = knn + ((size_t)b * N + n) * KNN;
        float mx = -3.4e38f, mn = 3.4e38f;
        #pragma unroll
        for (int j = 0; j < KNN; ++j) {
            float v = bvb[(size_t)kn[j] * O + o];
            mx = fmaxf(mx, v);
            mn = fminf(mn, v);
        }
        float a   = av[((size_t)b * N + n) * O + o];
        float sel = (scale >= 0.f) ? (a + mx) : (a + mn);
        float y   = fmaf(sel, scale, bias);
        y = fmaxf(y, NEG_SLOPE * y);
        lds[o][w * 16 + i] = y;
    }
    __syncthreads();
    int r  = threadIdx.x >> 2;
    int c0 = (threadIdx.x & 3) << 4;
    float* ob = out + (size_t)b * O * N + (size_t)r * N + n0;
    #pragma unroll
    for (int j = 0; j < 16; j += 4) {
        float4 v;
        v.x = lds[r][c0 + j + 0];
        v.y = lds[r][c0 + j + 1];
        v.z = lds[r][c0 + j + 2];
        v.w = lds[r][c0 + j + 3];
        *(float4*)(ob + c0 + j) = v;
    }
}

extern "C" void kernel_launch(void* const* d_in, const int* in_sizes, int n_in,
                              void* d_out, int out_size, void* d_ws, size_t ws_size,
                              hipStream_t stream) {
    const float* x     = (const float*)d_in[0];
    const float* W     = (const float*)d_in[1];
    const float* gamma = (const float*)d_in[2];
    const float* beta  = (const float*)d_in[3];
    const float* rmean = (const float*)d_in[4];
    const float* rvar  = (const float*)d_in[5];
    float* out = (float*)d_out;

    char* wsb = (char*)d_ws;
    float* Xt  = (float*)(wsb);                 //  8 MB
    float* sqn = (float*)(wsb + 8388608);       //  128 KB
    float* av  = (float*)(wsb + 8519680);       //  8 MB
    float* bvv = (float*)(wsb + 16908288);      //  8 MB
    int*   knn = (int*)  (wsb + 25296896);      //  2.5 MB
    char*  AHL =         (wsb + 27918336);      //  8 MB f16 hi/lo frag-major

    k_transpose<<<512, 256, 0, stream>>>(x, Xt, sqn, AHL);
    k_ab<<<256, 256, 0, stream>>>(Xt, W, av, bvv);
    k_knn<<<512, 256, 0, stream>>>(AHL, sqn, knn);
    k_out<<<512, 256, 0, stream>>>(av, bvv, knn, gamma, beta, rmean, rvar, out);
}